// Round 4
// baseline (3150.866 us; speedup 1.0000x reference)
//
#include <hip/hip_runtime.h>
#include <hip/hip_bf16.h>
#include <stdint.h>

#define TOK 8192      // B*N tokens
#define DIM 1024
#define NSEQ 4096
#define NH 8
#define DHD 128
#define NU 64         // buckets
#define DFF 4096
#define NBH 16        // B*H
#define QKVN 3072     // fused q|k|v width

typedef unsigned short u16;
typedef unsigned int u32;
typedef short bf16x8 __attribute__((ext_vector_type(8)));
typedef float f32x4 __attribute__((ext_vector_type(4)));

__device__ __forceinline__ float bu2f(u16 u) { return __uint_as_float(((u32)u) << 16); }
__device__ __forceinline__ u16 f2bu(float f) {
  union { __hip_bfloat16 b; u16 u; } cv; cv.b = __float2bfloat16(f); return cv.u;
}

typedef __attribute__((address_space(1))) void gvoid_t;
typedef __attribute__((address_space(3))) void lvoid_t;
__device__ __forceinline__ void gload16(void* lds, const void* g) {
#if __has_builtin(__builtin_amdgcn_global_load_lds)
  __builtin_amdgcn_global_load_lds((const gvoid_t*)g, (lvoid_t*)lds, 16, 0, 0);
#else
  const int l = threadIdx.x & 63;
  ((uint4*)lds)[l] = *(const uint4*)g;
#endif
}

// ---------------- weight transpose + fp32->bf16 : W[K][N] -> Wt[rowOff+N][K] ----------------
__global__ __launch_bounds__(256) void wtrans_kernel(const float* __restrict__ W,
    u16* __restrict__ Wt, int K, int N, int dStride, int rowOff)
{
  __shared__ float T[32][33];
  const int tid = threadIdx.x;
  const size_t soff = (size_t)blockIdx.z * K * N;
  const size_t doff = (size_t)blockIdx.z * dStride;
  const int n0 = blockIdx.x << 5, k0 = blockIdx.y << 5;
  const int r = tid >> 3, c4 = (tid & 7) << 2;
  float4 v = *(const float4*)(W + soff + (size_t)(k0 + r) * N + n0 + c4);
  T[r][c4] = v.x; T[r][c4 + 1] = v.y; T[r][c4 + 2] = v.z; T[r][c4 + 3] = v.w;
  __syncthreads();
  u32 lo = (u32)f2bu(T[c4][r]) | ((u32)f2bu(T[c4 + 1][r]) << 16);
  u32 hi = (u32)f2bu(T[c4 + 2][r]) | ((u32)f2bu(T[c4 + 3][r]) << 16);
  *(uint2*)(Wt + doff + (size_t)(rowOff + n0 + r) * K + k0 + c4) = make_uint2(lo, hi);
}

// ---------------- layernorm fp32 -> bf16 ----------------
__global__ __launch_bounds__(256) void ln_kernel(const float* __restrict__ x,
    const float* __restrict__ g, const float* __restrict__ bt, u16* __restrict__ h)
{
  const int row = blockIdx.x, tid = threadIdx.x;
  const int w = tid >> 6, l = tid & 63;
  float4 v = ((const float4*)(x + (size_t)row * DIM))[tid];
  float s = v.x + v.y + v.z + v.w;
  float s2 = v.x * v.x + v.y * v.y + v.z * v.z + v.w * v.w;
#pragma unroll
  for (int off = 32; off; off >>= 1) { s += __shfl_down(s, off); s2 += __shfl_down(s2, off); }
  __shared__ float ps[8];
  __shared__ float mv[2];
  if (l == 0) { ps[w] = s; ps[4 + w] = s2; }
  __syncthreads();
  if (tid == 0) {
    float S = ps[0] + ps[1] + ps[2] + ps[3];
    float S2 = ps[4] + ps[5] + ps[6] + ps[7];
    float mean = S * (1.f / 1024.f);
    float var = S2 * (1.f / 1024.f) - mean * mean;
    mv[0] = mean; mv[1] = rsqrtf(var + 1e-5f);
  }
  __syncthreads();
  const float mean = mv[0], inv = mv[1];
  const int c = tid * 4;
  float o0 = (v.x - mean) * inv * g[c + 0] + bt[c + 0];
  float o1 = (v.y - mean) * inv * g[c + 1] + bt[c + 1];
  float o2 = (v.z - mean) * inv * g[c + 2] + bt[c + 2];
  float o3 = (v.w - mean) * inv * g[c + 3] + bt[c + 3];
  u32 lo = (u32)f2bu(o0) | ((u32)f2bu(o1) << 16);
  u32 hi = (u32)f2bu(o2) | ((u32)f2bu(o3) << 16);
  ((uint2*)(h + (size_t)row * DIM))[tid] = make_uint2(lo, hi);
}

// ================= 256x256 8-phase GEMM (m201 schedule) =================
// A[M][K] x Bt[N][K] -> C[M][N].  BK=64, 8 waves (2Mx4N), 128KiB LDS,
// st_16x32 swizzle, 2 K-tiles per iter, one 4-load stage-group per phase,
// counted vmcnt(4) only at ph3/ph7 ends. EPI 0: bf16 ; EPI 2: gelu+bias bf16.
template<int EPI>
__global__ __launch_bounds__(512, 2) void gemm8_kernel(
    const u16* __restrict__ A, const u16* __restrict__ Bt, void* Cout,
    const float* __restrict__ bias, int M, int N, int K)
{
  __shared__ __align__(16) u16 As[2][2][8192];   // [dbuf][half][128*64]
  __shared__ __align__(16) u16 Bs[2][2][8192];
  const int tid = threadIdx.x;
  const int w = tid >> 6, l = tid & 63;
  const int wm = w >> 2, wn = w & 3;
  const int lr = l & 15, lk = (l >> 4) << 3;
  // bijective XCD swizzle (m204)
  const int gx = gridDim.x;
  const int nwg = gx * gridDim.y;
  const int orig = blockIdx.y * gx + blockIdx.x;
  const int qq = nwg >> 3, rr = nwg & 7, xcd = orig & 7, lin = orig >> 3;
  const int wg = (xcd < rr ? xcd * (qq + 1) : rr * (qq + 1) + (xcd - rr) * qq) + lin;
  const int brow = (wg / gx) << 8, bcol = (wg % gx) << 8;
  const int nk = K >> 6, nkp = nk >> 1;
  // staging source (pre-swizzled so linear LDS dest + swizzled read agree)
  const int srow = w * 8 + (l >> 3);
  const int scol = ((l & 7) * 8) ^ ((l & 32) ? 16 : 0);
  // fragment-read swizzle: flip col bit4 when row bit2 set (row bit2 == l bit2)
  const int swz = ((l >> 2) & 1) << 4;
  const int colK0 = lk ^ swz, colK1 = (32 + lk) ^ swz;

  f32x4 acc[8][4] = {};
  bf16x8 af[4][2];
  bf16x8 bf[2][2][2];

#define STAGE_A8(b_, kt_) { _Pragma("unroll") for (int h_ = 0; h_ < 2; ++h_)    \
    _Pragma("unroll") for (int c = 0; c < 2; ++c)                               \
    gload16(&As[b_][h_][c * 4096 + w * 512],                                    \
      A + (size_t)(brow + h_ * 128 + c * 64 + srow) * K + (kt_) * 64 + scol); }
#define STAGE_B8(b_, kt_) { _Pragma("unroll") for (int h_ = 0; h_ < 2; ++h_)    \
    _Pragma("unroll") for (int c = 0; c < 2; ++c)                               \
    gload16(&Bs[b_][h_][c * 4096 + w * 512],                                    \
      Bt + (size_t)(bcol + h_ * 128 + c * 64 + srow) * K + (kt_) * 64 + scol); }
#define LOAD_AF(b_, mh_) { _Pragma("unroll") for (int m = 0; m < 4; ++m) {      \
    const u16* p_ = &As[b_][wm][((mh_) * 64 + m * 16 + lr) * 64];               \
    af[m][0] = *(const bf16x8*)(p_ + colK0);                                    \
    af[m][1] = *(const bf16x8*)(p_ + colK1); } }
#define LOAD_BF(b_, nh_) { _Pragma("unroll") for (int n = 0; n < 2; ++n) {      \
    const u16* p_ = &Bs[b_][wn >> 1][((wn & 1) * 64 + (nh_) * 32 + n * 16 + lr) * 64]; \
    bf[nh_][n][0] = *(const bf16x8*)(p_ + colK0);                               \
    bf[nh_][n][1] = *(const bf16x8*)(p_ + colK1); } }
// k-half outermost: 8 independent acc chains between dependent MFMAs
#define MFMA_Q(mh_, nh_) { __builtin_amdgcn_s_setprio(1);                       \
    _Pragma("unroll") for (int kk = 0; kk < 2; ++kk)                            \
    _Pragma("unroll") for (int m = 0; m < 4; ++m)                               \
    _Pragma("unroll") for (int n = 0; n < 2; ++n)                               \
      acc[(mh_)*4+m][(nh_)*2+n] = __builtin_amdgcn_mfma_f32_16x16x32_bf16(      \
          af[m][kk], bf[nh_][n][kk], acc[(mh_)*4+m][(nh_)*2+n], 0, 0, 0);       \
    __builtin_amdgcn_s_setprio(0); }
#define BAR() __builtin_amdgcn_s_barrier()
#define LGKM0() asm volatile("s_waitcnt lgkmcnt(0)" ::: "memory")

  // prologue: A(0)->b0, B(0)->b0, A(1)->b1 (3 groups); gate A0,B0, allow A1
  STAGE_A8(0, 0);
  STAGE_B8(0, 0);
  STAGE_A8(1, 1);
  asm volatile("s_waitcnt vmcnt(4)" ::: "memory");
  BAR();

  for (int i = 0; i < nkp; ++i) {
    const int t0 = 2 * i;
    // ---- ph0 (tile t0, buf0): quadrant (0,0); stage B(t0+1)->b1
    LOAD_AF(0, 0); LOAD_BF(0, 0);
    STAGE_B8(1, t0 + 1);
    BAR(); LGKM0();
    MFMA_Q(0, 0);
    BAR();
    // ---- ph1: quadrant (0,1)
    LOAD_BF(0, 1);
    BAR(); LGKM0();
    MFMA_Q(0, 1);
    BAR();
    // ---- ph2: quadrant (1,0)
    LOAD_AF(0, 1);
    BAR(); LGKM0();
    MFMA_Q(1, 0);
    BAR();
    // ---- ph3: quadrant (1,1); stage A(t0+2)->b0; gate b1 (A(t0+1),B(t0+1) landed)
    if (t0 + 2 < nk) STAGE_A8(0, t0 + 2);
    BAR(); LGKM0();
    MFMA_Q(1, 1);
    if (i + 1 < nkp) { asm volatile("s_waitcnt vmcnt(4)" ::: "memory"); }
    else             { asm volatile("s_waitcnt vmcnt(0)" ::: "memory"); }
    BAR();
    // ---- ph4 (tile t0+1, buf1): quadrant (0,0); stage B(t0+2)->b0
    LOAD_AF(1, 0); LOAD_BF(1, 0);
    if (t0 + 2 < nk) STAGE_B8(0, t0 + 2);
    BAR(); LGKM0();
    MFMA_Q(0, 0);
    BAR();
    // ---- ph5: quadrant (0,1)
    LOAD_BF(1, 1);
    BAR(); LGKM0();
    MFMA_Q(0, 1);
    BAR();
    // ---- ph6: quadrant (1,0)
    LOAD_AF(1, 1);
    BAR(); LGKM0();
    MFMA_Q(1, 0);
    BAR();
    // ---- ph7: quadrant (1,1); stage A(t0+3)->b1; gate b0 (A(t0+2),B(t0+2) landed)
    if (t0 + 3 < nk) STAGE_A8(1, t0 + 3);
    BAR(); LGKM0();
    MFMA_Q(1, 1);
    asm volatile("s_waitcnt vmcnt(4)" ::: "memory");
    BAR();
  }
#undef STAGE_A8
#undef STAGE_B8
#undef LOAD_AF
#undef LOAD_BF
#undef MFMA_Q
#undef BAR
#undef LGKM0

  const int l4 = (l >> 4) << 2;
#pragma unroll
  for (int mi = 0; mi < 8; ++mi) {
#pragma unroll
    for (int nj = 0; nj < 4; ++nj) {
      int col = bcol + wn * 64 + nj * 16 + lr;
#pragma unroll
      for (int r = 0; r < 4; ++r) {
        int row = brow + wm * 128 + mi * 16 + l4 + r;
        size_t idx = (size_t)row * N + col;
        float v0 = acc[mi][nj][r];
        if (EPI == 0) {
          ((u16*)Cout)[idx] = f2bu(v0);
        } else {
          float tt = v0 + bias[col];
          ((u16*)Cout)[idx] = f2bu(0.5f * tt * (1.0f + erff(tt * 0.70710678118654752f)));
        }
      }
    }
  }
}

// ---------------- bf16 GEMM, m97 structure + XCD swizzle (N=1024 GEMMs) ----------
// EPI 1: C=AB+bias+res -> f32
__global__ __launch_bounds__(256, 2) void gemm_kernel(
    const u16* __restrict__ A, const u16* __restrict__ Bt, void* Cout,
    const float* __restrict__ bias, const float* res, int M, int N, int K)
{
  __shared__ __align__(16) u16 As[2][128 * 32];
  __shared__ __align__(16) u16 Bs[2][128 * 32];
  const int tid = threadIdx.x;
  const int w = tid >> 6, l = tid & 63;
  const int gx = gridDim.x;
  const int nwg = gx * gridDim.y;
  const int orig = blockIdx.y * gx + blockIdx.x;
  const int qq = nwg >> 3, rr = nwg & 7, xcd = orig & 7, lin = orig >> 3;
  const int wg = (xcd < rr ? xcd * (qq + 1) : rr * (qq + 1) + (xcd - rr) * qq) + lin;
  const int brow = (wg / gx) << 7, bcol = (wg % gx) << 7;
  const int wr = (w >> 1) << 6, wc = (w & 1) << 6;
  const int lr = l & 15, lk = (l >> 4) << 3;
  f32x4 acc[4][4] = {};
  const int nk = K >> 5;

#define STAGE_G(buf, kt)                                                        \
  {                                                                             \
    _Pragma("unroll")                                                           \
    for (int j = 0; j < 2; ++j) {                                               \
      int c = j * 256 + tid;                                                    \
      int rrow = c >> 2, k8 = (c & 3) << 3;                                     \
      int ub = (j * 256 + w * 64) * 8;                                          \
      gload16(&As[buf][ub], A + (size_t)(brow + rrow) * K + (kt) * 32 + k8);    \
      gload16(&Bs[buf][ub], Bt + (size_t)(bcol + rrow) * K + (kt) * 32 + k8);   \
    }                                                                           \
  }

  STAGE_G(0, 0);
  __syncthreads();
  for (int kt = 0; kt < nk; ++kt) {
    int buf = kt & 1;
    if (kt + 1 < nk) STAGE_G(buf ^ 1, kt + 1);
    bf16x8 a[4], bb[4];
#pragma unroll
    for (int m = 0; m < 4; ++m) a[m] = *(const bf16x8*)&As[buf][(wr + m * 16 + lr) * 32 + lk];
#pragma unroll
    for (int n = 0; n < 4; ++n) bb[n] = *(const bf16x8*)&Bs[buf][(wc + n * 16 + lr) * 32 + lk];
#pragma unroll
    for (int m = 0; m < 4; ++m)
#pragma unroll
      for (int n = 0; n < 4; ++n)
        acc[m][n] = __builtin_amdgcn_mfma_f32_16x16x32_bf16(a[m], bb[n], acc[m][n], 0, 0, 0);
    __syncthreads();
  }
#undef STAGE_G
  const int l4 = (l >> 4) << 2;
#pragma unroll
  for (int m = 0; m < 4; ++m) {
#pragma unroll
    for (int n = 0; n < 4; ++n) {
      int col = bcol + wc + n * 16 + lr;
#pragma unroll
      for (int r = 0; r < 4; ++r) {
        int row = brow + wr + m * 16 + l4 + r;
        size_t idx = (size_t)row * N + col;
        ((float*)Cout)[idx] = acc[m][n][r] + bias[col] + res[idx];
      }
    }
  }
}

// ---------------- attention: q softmax (q rows at stride QKVN) ----------------
__global__ __launch_bounds__(256) void qsoftmax_kernel(const u16* __restrict__ qkv, u16* __restrict__ qs)
{
  const int w = threadIdx.x >> 6, l = threadIdx.x & 63;
  const size_t gid = (size_t)blockIdx.x * 4 + w;
  const size_t tok = gid >> 3;
  const int h = (int)(gid & 7);
  const u16* row = qkv + tok * QKVN + h * 128;
  u16* orow = qs + tok * DIM + h * 128;
  u32 p = *(const u32*)(row + l * 2);
  float f0 = bu2f((u16)(p & 0xffff)), f1 = bu2f((u16)(p >> 16));
  float m = fmaxf(f0, f1);
#pragma unroll
  for (int off = 32; off; off >>= 1) m = fmaxf(m, __shfl_xor(m, off));
  float e0 = expf(f0 - m), e1 = expf(f1 - m);
  float s = e0 + e1;
#pragma unroll
  for (int off = 32; off; off >>= 1) s += __shfl_xor(s, off);
  float sc = 0.08838834764831845f / s;   // (1/sqrt(128)) / sum
  u32 o = (u32)f2bu(e0 * sc) | ((u32)f2bu(e1 * sc) << 16);
  *(u32*)(orow + l * 2) = o;
}

// ---------------- exp(k), v : rows at stride QKVN -> transposed [bh][e][n] bf16 ----------------
__global__ __launch_bounds__(256) void kvt_kernel(
    const u16* __restrict__ kin, const u16* __restrict__ vin,
    u16* __restrict__ ket, u16* __restrict__ vt)
{
  __shared__ u16 T[128 * 72];
  const int tid = threadIdx.x;
  const int t64 = blockIdx.x, bh = blockIdx.y;
  const int b = bh >> 3, h = bh & 7;
  for (int pass = 0; pass < 2; ++pass) {
    const u16* src = pass ? vin : kin;
    u16* dst = pass ? vt : ket;
    if (pass) __syncthreads();
#pragma unroll
    for (int j = 0; j < 4; ++j) {
      int c = j * 256 + tid;
      int i = c >> 4, e8 = (c & 15) << 3;
      bf16x8 dv = *(const bf16x8*)(src + ((size_t)(b * NSEQ + t64 * 64 + i)) * QKVN + h * 128 + e8);
#pragma unroll
      for (int jj = 0; jj < 8; ++jj) {
        float f = bu2f((u16)dv[jj]);
        if (pass == 0) f = expf(f);
        T[(e8 + jj) * 72 + i] = f2bu(f);
      }
    }
    __syncthreads();
#pragma unroll
    for (int j = 0; j < 4; ++j) {
      int c = j * 256 + tid;
      int e = c >> 3, n8 = (c & 7) << 3;
      bf16x8 o;
#pragma unroll
      for (int jj = 0; jj < 8; ++jj) o[jj] = (short)T[e * 72 + n8 + jj];
      *(bf16x8*)(dst + ((size_t)(bh * 128 + e)) * NSEQ + t64 * 64 + n8) = o;
    }
  }
}

// ---------------- per-bucket k sums ----------------
__global__ void ksum_kernel(const u16* __restrict__ ket, float* __restrict__ Ksum)
{
  const int u = blockIdx.x, bh = blockIdx.y, e = threadIdx.x;  // 128 threads
  const u16* p = ket + ((size_t)(bh * 128 + e)) * NSEQ + u * 64;
  float s = 0.f;
#pragma unroll
  for (int i = 0; i < 64; ++i) s += bu2f(p[i]);
  Ksum[(((size_t)bh * 64 + u) << 7) + e] = s;
}

// ---------------- exclusive cumsum of k sums over buckets ----------------
__global__ void kc_kernel(const float* __restrict__ Ksum, float* __restrict__ Kc)
{
  const int bh = blockIdx.x, e = threadIdx.x;
  float run = 0.f;
  for (int u = 0; u < 64; ++u) {
    size_t i = (((size_t)bh * 64 + u) << 7) + e;
    Kc[i] = run;
    run += Ksum[i];
  }
}

// ---------------- per-bucket ctx^T[e][d] = sum_i v[i,e]*ke[i,d] (MFMA) ----------------
__global__ __launch_bounds__(256, 2) void ctx_kernel(
    const u16* __restrict__ vt, const u16* __restrict__ ket, u16* __restrict__ ctxT)
{
  __shared__ __align__(16) u16 Av[128 * 64];
  __shared__ __align__(16) u16 Bk[128 * 64];
  const int tid = threadIdx.x, w = tid >> 6, l = tid & 63;
  const int u = blockIdx.x, bh = blockIdx.y;
  const int lr = l & 15, lk = (l >> 4) << 3;
#pragma unroll
  for (int j = 0; j < 4; ++j) {
    int c = j * 256 + tid;
    int row = c >> 3, i8 = (c & 7) << 3;
    size_t goff = ((size_t)(bh * 128 + row)) * NSEQ + u * 64 + i8;
    int ub = (j * 256 + w * 64) * 8;
    gload16(&Av[ub], vt + goff);
    gload16(&Bk[ub], ket + goff);
  }
  __syncthreads();
  const int wr = (w >> 1) << 6, wc = (w & 1) << 6;
  f32x4 acc[4][4] = {};
#pragma unroll
  for (int ks = 0; ks < 2; ++ks) {
    bf16x8 a[4], bb[4];
#pragma unroll
    for (int m = 0; m < 4; ++m) a[m] = *(const bf16x8*)&Av[(wr + m * 16 + lr) * 64 + ks * 32 + lk];
#pragma unroll
    for (int n = 0; n < 4; ++n) bb[n] = *(const bf16x8*)&Bk[(wc + n * 16 + lr) * 64 + ks * 32 + lk];
#pragma unroll
    for (int m = 0; m < 4; ++m)
#pragma unroll
      for (int n = 0; n < 4; ++n)
        acc[m][n] = __builtin_amdgcn_mfma_f32_16x16x32_bf16(a[m], bb[n], acc[m][n], 0, 0, 0);
  }
  u16* out = ctxT + ((size_t)(bh * 64 + u) << 14);
  const int l4 = (l >> 4) << 2;
#pragma unroll
  for (int m = 0; m < 4; ++m)
#pragma unroll
    for (int n = 0; n < 4; ++n)
#pragma unroll
      for (int r = 0; r < 4; ++r) {
        int e = wr + m * 16 + l4 + r, d = wc + n * 16 + lr;
        out[e * 128 + d] = f2bu(acc[m][n][r]);
      }
}

// ---------------- exclusive cumsum of ctx over buckets ----------------
__global__ void cumsum_kernel(const u16* __restrict__ ctxT, u16* __restrict__ ctxc)
{
  const size_t base = ((size_t)blockIdx.y << 20) + (size_t)blockIdx.x * 256 + threadIdx.x;
  const u16* src = ctxT + base;
  u16* dst = ctxc + base;
  float run = 0.f;
  for (int u = 0; u < 64; ++u) {
    u16 cvv = src[(size_t)u << 14];
    dst[(size_t)u << 14] = f2bu(run);
    run += bu2f(cvv);
  }
}

// ---------------- out[n][e] = D_inv[n] * sum_d qs[n,d]*ctxc[d][e] (MFMA) ----------------
__global__ __launch_bounds__(256, 2) void attnout_kernel(
    const u16* __restrict__ qs, const u16* __restrict__ ctxc,
    const float* __restrict__ Kc, u16* __restrict__ aout)
{
  __shared__ __align__(16) u16 Aq[64 * 128];
  __shared__ __align__(16) u16 Bc[128 * 128];
  __shared__ float KcS[128];
  __shared__ float Dinv[64];
  const int tid = threadIdx.x, w = tid >> 6, l = tid & 63;
  const int u = blockIdx.x, bh = blockIdx.y;
  const int b = bh >> 3, h = bh & 7;
  const int lr = l & 15, lk = (l >> 4) << 3;
#pragma unroll
  for (int j = 0; j < 4; ++j) {
    int c = j * 256 + tid;
    int n = c >> 4, d8 = (c & 15) << 3;
    gload16(&Aq[(j * 256 + w * 64) * 8],
            qs + ((size_t)(b * NSEQ + u * 64 + n)) * DIM + h * 128 + d8);
  }
  const u16* csrc = ctxc + ((size_t)(bh * 64 + u) << 14);
#pragma unroll
  for (int j = 0; j < 8; ++j) {
    int c = j * 256 + tid;
    gload16(&Bc[(j * 256 + w * 64) * 8], csrc + (size_t)c * 8);
  }
  if (tid < 128) KcS[tid] = Kc[(((size_t)bh * 64 + u) << 7) + tid];
  __syncthreads();
  if (tid < 64) {
    float s = 0.f;
#pragma unroll
    for (int dd = 0; dd < 128; ++dd) {
      int d = (dd + tid * 2) & 127;   // rotate to dodge LDS bank conflicts
      s += bu2f(Aq[tid * 128 + d]) * KcS[d];
    }
    Dinv[tid] = 1.f / fmaxf(s, 1e-3f);
  }
  __syncthreads();
  f32x4 acc[4][2] = {};
#pragma unroll
  for (int ks = 0; ks < 4; ++ks) {
    bf16x8 a[4], bb[2];
#pragma unroll
    for (int m = 0; m < 4; ++m) a[m] = *(const bf16x8*)&Aq[(m * 16 + lr) * 128 + ks * 32 + lk];
#pragma unroll
    for (int n = 0; n < 2; ++n) bb[n] = *(const bf16x8*)&Bc[(w * 32 + n * 16 + lr) * 128 + ks * 32 + lk];
#pragma unroll
    for (int m = 0; m < 4; ++m)
#pragma unroll
      for (int n = 0; n < 2; ++n)
        acc[m][n] = __builtin_amdgcn_mfma_f32_16x16x32_bf16(a[m], bb[n], acc[m][n], 0, 0, 0);
  }
  const int l4 = (l >> 4) << 2;
#pragma unroll
  for (int m = 0; m < 4; ++m)
#pragma unroll
    for (int n = 0; n < 2; ++n)
#pragma unroll
      for (int r = 0; r < 4; ++r) {
        int nrow = m * 16 + l4 + r;
        int e = w * 32 + n * 16 + lr;
        float v = acc[m][n][r] * Dinv[nrow];
        aout[((size_t)(b * NSEQ + u * 64 + nrow)) * DIM + h * 128 + e] = f2bu(v);
      }
}

extern "C" void kernel_launch(void* const* d_in, const int* in_sizes, int n_in,
                              void* d_out, int out_size, void* d_ws, size_t ws_size,
                              hipStream_t stream)
{
  (void)in_sizes; (void)n_in; (void)out_size; (void)ws_size;
  const float* x_in = (const float*)d_in[0];
  const float* ln1g = (const float*)d_in[1];
  const float* ln1b = (const float*)d_in[2];
  const float* Wq   = (const float*)d_in[3];
  const float* Wk   = (const float*)d_in[4];
  const float* Wv   = (const float*)d_in[5];
  const float* Wo   = (const float*)d_in[6];
  const float* bo   = (const float*)d_in[7];
  const float* ln2g = (const float*)d_in[8];
  const float* ln2b = (const float*)d_in[9];
  const float* W1   = (const float*)d_in[10];
  const float* b1   = (const float*)d_in[11];
  const float* W2   = (const float*)d_in[12];
  const float* b2   = (const float*)d_in[13];
  float* x = (float*)d_out;

  char* ws = (char*)d_ws;
  size_t off = 0;
  auto alloc = [&](size_t bytes) -> char* {
    char* p = ws + off;
    off += (bytes + 255) & ~(size_t)255;
    return p;
  };
  const size_t SW = (size_t)6 * 1024 * 1024;   // small weight elems (per 6 layers)
  const size_t BW = (size_t)6 * 4096 * 1024;   // big weight elems
  u16* Wqkvt = (u16*)alloc(SW * 3 * 2);        // fused [6][3072][1024]
  u16* Wot = (u16*)alloc(SW * 2);
  u16* W1t = (u16*)alloc(BW * 2);
  u16* W2t = (u16*)alloc(BW * 2);
  u16* hbuf = (u16*)alloc((size_t)TOK * DIM * 2);
  u16* qsb  = (u16*)alloc((size_t)TOK * DIM * 2);
  u16* ket  = (u16*)alloc((size_t)TOK * DIM * 2);
  u16* vtb  = (u16*)alloc((size_t)TOK * DIM * 2);
  u16* ab   = (u16*)alloc((size_t)TOK * DIM * 2);
  float* Ksum = (float*)alloc((size_t)NBH * 64 * 128 * 4);
  float* Kc   = (float*)alloc((size_t)NBH * 64 * 128 * 4);
  char* R = alloc((size_t)TOK * DFF * 2);      // 67MB union region
  u16* qkvb = (u16*)R;                                   // phase 1: fused qkv bf16 [8192][3072]
  u16* ctxT = (u16*)R;                                   // phase 2: ctx buffers
  u16* ctxc = (u16*)(R + ((size_t)NBH * 64 * 128 * 128) * 2);
  u16* mid  = (u16*)R;                                   // phase 3: ffn mid

  // one-time (per call) weight transpose + bf16 conversion
  wtrans_kernel<<<dim3(32, 32, 6), 256, 0, stream>>>(Wq, Wqkvt, 1024, 1024, QKVN * 1024, 0);
  wtrans_kernel<<<dim3(32, 32, 6), 256, 0, stream>>>(Wk, Wqkvt, 1024, 1024, QKVN * 1024, 1024);
  wtrans_kernel<<<dim3(32, 32, 6), 256, 0, stream>>>(Wv, Wqkvt, 1024, 1024, QKVN * 1024, 2048);
  wtrans_kernel<<<dim3(32, 32, 6), 256, 0, stream>>>(Wo, Wot, 1024, 1024, 1024 * 1024, 0);
  wtrans_kernel<<<dim3(128, 32, 6), 256, 0, stream>>>(W1, W1t, 1024, 4096, 4096 * 1024, 0);
  wtrans_kernel<<<dim3(32, 128, 6), 256, 0, stream>>>(W2, W2t, 4096, 1024, 4096 * 1024, 0);
  hipMemcpyAsync(x, x_in, (size_t)TOK * DIM * 4, hipMemcpyDeviceToDevice, stream);

  for (int d = 0; d < 6; ++d) {
    ln_kernel<<<TOK, 256, 0, stream>>>(x, ln1g + d * DIM, ln1b + d * DIM, hbuf);
    gemm8_kernel<0><<<dim3(12, 32), 512, 0, stream>>>(hbuf, Wqkvt + (size_t)d * QKVN * 1024, qkvb, nullptr, TOK, QKVN, DIM);
    qsoftmax_kernel<<<TOK * NH / 4, 256, 0, stream>>>(qkvb, qsb);
    kvt_kernel<<<dim3(64, NBH), 256, 0, stream>>>(qkvb + 1024, qkvb + 2048, ket, vtb);
    ksum_kernel<<<dim3(64, NBH), 128, 0, stream>>>(ket, Ksum);
    kc_kernel<<<NBH, 128, 0, stream>>>(Ksum, Kc);
    ctx_kernel<<<dim3(64, NBH), 256, 0, stream>>>(vtb, ket, ctxT);
    cumsum_kernel<<<dim3(64, NBH), 256, 0, stream>>>(ctxT, ctxc);
    attnout_kernel<<<dim3(64, NBH), 256, 0, stream>>>(qsb, ctxc, Kc, ab);
    gemm_kernel<<<dim3(8, 64), 256, 0, stream>>>(ab, Wot + (size_t)d * 1024 * 1024, x, bo + d * DIM, x, TOK, DIM, DIM);
    ln_kernel<<<TOK, 256, 0, stream>>>(x, ln2g + d * DIM, ln2b + d * DIM, hbuf);
    gemm8_kernel<2><<<dim3(16, 32), 512, 0, stream>>>(hbuf, W1t + (size_t)d * DFF * 1024, mid, b1 + d * DFF, TOK, DFF, DIM);
    gemm_kernel<<<dim3(8, 64), 256, 0, stream>>>(mid, W2t + (size_t)d * DFF * 1024, x, b2 + d * DIM, x, TOK, DIM, DFF);
  }
}

// Round 5
// 3076.508 us; speedup vs baseline: 1.0242x; 1.0242x over previous
//
#include <hip/hip_runtime.h>
#include <hip/hip_bf16.h>
#include <stdint.h>

#define TOK 8192      // B*N tokens
#define DIM 1024
#define NSEQ 4096
#define NH 8
#define DHD 128
#define NU 64         // buckets
#define DFF 4096
#define NBH 16        // B*H
#define QKVN 3072     // fused q|k|v width

typedef unsigned short u16;
typedef unsigned int u32;
typedef short bf16x8 __attribute__((ext_vector_type(8)));
typedef float f32x4 __attribute__((ext_vector_type(4)));

__device__ __forceinline__ float bu2f(u16 u) { return __uint_as_float(((u32)u) << 16); }
__device__ __forceinline__ u16 f2bu(float f) {
  union { __hip_bfloat16 b; u16 u; } cv; cv.b = __float2bfloat16(f); return cv.u;
}

typedef __attribute__((address_space(1))) void gvoid_t;
typedef __attribute__((address_space(3))) void lvoid_t;
__device__ __forceinline__ void gload16(void* lds, const void* g) {
#if __has_builtin(__builtin_amdgcn_global_load_lds)
  __builtin_amdgcn_global_load_lds((const gvoid_t*)g, (lvoid_t*)lds, 16, 0, 0);
#else
  const int l = threadIdx.x & 63;
  ((uint4*)lds)[l] = *(const uint4*)g;
#endif
}

// ---------------- weight transpose + fp32->bf16 : W[K][N] -> Wt[rowOff+N][K] ----------------
__global__ __launch_bounds__(256) void wtrans_kernel(const float* __restrict__ W,
    u16* __restrict__ Wt, int K, int N, int dStride, int rowOff)
{
  __shared__ float T[32][33];
  const int tid = threadIdx.x;
  const size_t soff = (size_t)blockIdx.z * K * N;
  const size_t doff = (size_t)blockIdx.z * dStride;
  const int n0 = blockIdx.x << 5, k0 = blockIdx.y << 5;
  const int r = tid >> 3, c4 = (tid & 7) << 2;
  float4 v = *(const float4*)(W + soff + (size_t)(k0 + r) * N + n0 + c4);
  T[r][c4] = v.x; T[r][c4 + 1] = v.y; T[r][c4 + 2] = v.z; T[r][c4 + 3] = v.w;
  __syncthreads();
  u32 lo = (u32)f2bu(T[c4][r]) | ((u32)f2bu(T[c4 + 1][r]) << 16);
  u32 hi = (u32)f2bu(T[c4 + 2][r]) | ((u32)f2bu(T[c4 + 3][r]) << 16);
  *(uint2*)(Wt + doff + (size_t)(rowOff + n0 + r) * K + k0 + c4) = make_uint2(lo, hi);
}

// ---------------- layernorm fp32 -> bf16 ----------------
__global__ __launch_bounds__(256) void ln_kernel(const float* __restrict__ x,
    const float* __restrict__ g, const float* __restrict__ bt, u16* __restrict__ h)
{
  const int row = blockIdx.x, tid = threadIdx.x;
  const int w = tid >> 6, l = tid & 63;
  float4 v = ((const float4*)(x + (size_t)row * DIM))[tid];
  float s = v.x + v.y + v.z + v.w;
  float s2 = v.x * v.x + v.y * v.y + v.z * v.z + v.w * v.w;
#pragma unroll
  for (int off = 32; off; off >>= 1) { s += __shfl_down(s, off); s2 += __shfl_down(s2, off); }
  __shared__ float ps[8];
  __shared__ float mv[2];
  if (l == 0) { ps[w] = s; ps[4 + w] = s2; }
  __syncthreads();
  if (tid == 0) {
    float S = ps[0] + ps[1] + ps[2] + ps[3];
    float S2 = ps[4] + ps[5] + ps[6] + ps[7];
    float mean = S * (1.f / 1024.f);
    float var = S2 * (1.f / 1024.f) - mean * mean;
    mv[0] = mean; mv[1] = rsqrtf(var + 1e-5f);
  }
  __syncthreads();
  const float mean = mv[0], inv = mv[1];
  const int c = tid * 4;
  float o0 = (v.x - mean) * inv * g[c + 0] + bt[c + 0];
  float o1 = (v.y - mean) * inv * g[c + 1] + bt[c + 1];
  float o2 = (v.z - mean) * inv * g[c + 2] + bt[c + 2];
  float o3 = (v.w - mean) * inv * g[c + 3] + bt[c + 3];
  u32 lo = (u32)f2bu(o0) | ((u32)f2bu(o1) << 16);
  u32 hi = (u32)f2bu(o2) | ((u32)f2bu(o3) << 16);
  ((uint2*)(h + (size_t)row * DIM))[tid] = make_uint2(lo, hi);
}

// ================= 256x256 8-phase GEMM (m201 schedule, full 3-bit row swizzle) ========
// A[M][K] x Bt[N][K] -> C[M][N].  BK=64, 8 waves (2Mx4N), 128KiB LDS.
// LDS swizzle: physical bytecol = logical ^ ((row&7)<<4). A fragment b128 read's 64
// lanes (row r=l&7 x2, slot s=l>>4) hit granule s^r -> 8 lanes/granule = all 32 banks.
// EPI 0: bf16 ; EPI 2: gelu+bias bf16.
template<int EPI>
__global__ __launch_bounds__(512, 2) void gemm8_kernel(
    const u16* __restrict__ A, const u16* __restrict__ Bt, void* Cout,
    const float* __restrict__ bias, int M, int N, int K)
{
  __shared__ __align__(16) u16 As[2][2][8192];   // [dbuf][half][128*64]
  __shared__ __align__(16) u16 Bs[2][2][8192];
  const int tid = threadIdx.x;
  const int w = tid >> 6, l = tid & 63;
  const int wm = w >> 2, wn = w & 3;
  const int lr = l & 15, lk = (l >> 4) << 3;
  // bijective XCD swizzle (m204)
  const int gx = gridDim.x;
  const int nwg = gx * gridDim.y;
  const int orig = blockIdx.y * gx + blockIdx.x;
  const int qq = nwg >> 3, rr = nwg & 7, xcd = orig & 7, lin = orig >> 3;
  const int wg = (xcd < rr ? xcd * (qq + 1) : rr * (qq + 1) + (xcd - rr) * qq) + lin;
  const int brow = (wg / gx) << 8, bcol = (wg % gx) << 8;
  const int nk = K >> 6, nkp = nk >> 1;
  // staging: LDS dest linear (row = w*8+(l>>3) per 64-row group, 16B/lane);
  // global source col pre-swizzled with the SAME involution (row&7 = (l>>3)&7):
  const int srow = w * 8 + (l >> 3);
  const int scol = (((l & 7) ^ ((l >> 3) & 7)) << 3);
  // fragment-read swizzle: col_u16 ^= (row&7)<<3  (row&7 == l&7 for all fragment rows)
  const int rsw = (l & 7) << 3;
  const int colK0 = lk ^ rsw, colK1 = (32 + lk) ^ rsw;

  f32x4 acc[8][4] = {};
  bf16x8 af[4][2];
  bf16x8 bf[2][2][2];

#define STAGE_A8(b_, kt_) { _Pragma("unroll") for (int h_ = 0; h_ < 2; ++h_)    \
    _Pragma("unroll") for (int c = 0; c < 2; ++c)                               \
    gload16(&As[b_][h_][c * 4096 + w * 512],                                    \
      A + (size_t)(brow + h_ * 128 + c * 64 + srow) * K + (kt_) * 64 + scol); }
#define STAGE_B8(b_, kt_) { _Pragma("unroll") for (int h_ = 0; h_ < 2; ++h_)    \
    _Pragma("unroll") for (int c = 0; c < 2; ++c)                               \
    gload16(&Bs[b_][h_][c * 4096 + w * 512],                                    \
      Bt + (size_t)(bcol + h_ * 128 + c * 64 + srow) * K + (kt_) * 64 + scol); }
#define LOAD_AF(b_, mh_) { _Pragma("unroll") for (int m = 0; m < 4; ++m) {      \
    const u16* p_ = &As[b_][wm][((mh_) * 64 + m * 16 + lr) * 64];               \
    af[m][0] = *(const bf16x8*)(p_ + colK0);                                    \
    af[m][1] = *(const bf16x8*)(p_ + colK1); } }
#define LOAD_BF(b_, nh_) { _Pragma("unroll") for (int n = 0; n < 2; ++n) {      \
    const u16* p_ = &Bs[b_][wn >> 1][((wn & 1) * 64 + (nh_) * 32 + n * 16 + lr) * 64]; \
    bf[nh_][n][0] = *(const bf16x8*)(p_ + colK0);                               \
    bf[nh_][n][1] = *(const bf16x8*)(p_ + colK1); } }
// k-half outermost: 8 independent acc chains between dependent MFMAs
#define MFMA_Q(mh_, nh_) { __builtin_amdgcn_s_setprio(1);                       \
    _Pragma("unroll") for (int kk = 0; kk < 2; ++kk)                            \
    _Pragma("unroll") for (int m = 0; m < 4; ++m)                               \
    _Pragma("unroll") for (int n = 0; n < 2; ++n)                               \
      acc[(mh_)*4+m][(nh_)*2+n] = __builtin_amdgcn_mfma_f32_16x16x32_bf16(      \
          af[m][kk], bf[nh_][n][kk], acc[(mh_)*4+m][(nh_)*2+n], 0, 0, 0);       \
    __builtin_amdgcn_s_setprio(0); }
#define BAR() __builtin_amdgcn_s_barrier()
#define LGKM0() asm volatile("s_waitcnt lgkmcnt(0)" ::: "memory")

  // prologue: A(0)->b0, B(0)->b0, A(1)->b1 (3 groups); gate A0,B0, allow A1
  STAGE_A8(0, 0);
  STAGE_B8(0, 0);
  STAGE_A8(1, 1);
  asm volatile("s_waitcnt vmcnt(4)" ::: "memory");
  BAR();

  for (int i = 0; i < nkp; ++i) {
    const int t0 = 2 * i;
    // ---- ph0 (tile t0, buf0): quadrant (0,0); stage B(t0+1)->b1
    LOAD_AF(0, 0); LOAD_BF(0, 0);
    STAGE_B8(1, t0 + 1);
    BAR(); LGKM0();
    MFMA_Q(0, 0);
    BAR();
    // ---- ph1: quadrant (0,1)
    LOAD_BF(0, 1);
    BAR(); LGKM0();
    MFMA_Q(0, 1);
    BAR();
    // ---- ph2: quadrant (1,0)
    LOAD_AF(0, 1);
    BAR(); LGKM0();
    MFMA_Q(1, 0);
    BAR();
    // ---- ph3: quadrant (1,1); stage A(t0+2)->b0; gate b1 (A(t0+1),B(t0+1) landed)
    if (t0 + 2 < nk) STAGE_A8(0, t0 + 2);
    BAR(); LGKM0();
    MFMA_Q(1, 1);
    if (i + 1 < nkp) { asm volatile("s_waitcnt vmcnt(4)" ::: "memory"); }
    else             { asm volatile("s_waitcnt vmcnt(0)" ::: "memory"); }
    BAR();
    // ---- ph4 (tile t0+1, buf1): quadrant (0,0); stage B(t0+2)->b0
    LOAD_AF(1, 0); LOAD_BF(1, 0);
    if (t0 + 2 < nk) STAGE_B8(0, t0 + 2);
    BAR(); LGKM0();
    MFMA_Q(0, 0);
    BAR();
    // ---- ph5: quadrant (0,1)
    LOAD_BF(1, 1);
    BAR(); LGKM0();
    MFMA_Q(0, 1);
    BAR();
    // ---- ph6: quadrant (1,0)
    LOAD_AF(1, 1);
    BAR(); LGKM0();
    MFMA_Q(1, 0);
    BAR();
    // ---- ph7: quadrant (1,1); stage A(t0+3)->b1; gate b0 (A(t0+2),B(t0+2) landed)
    if (t0 + 3 < nk) STAGE_A8(1, t0 + 3);
    BAR(); LGKM0();
    MFMA_Q(1, 1);
    asm volatile("s_waitcnt vmcnt(4)" ::: "memory");
    BAR();
  }
#undef STAGE_A8
#undef STAGE_B8
#undef LOAD_AF
#undef LOAD_BF
#undef MFMA_Q
#undef BAR
#undef LGKM0

  const int l4 = (l >> 4) << 2;
#pragma unroll
  for (int mi = 0; mi < 8; ++mi) {
#pragma unroll
    for (int nj = 0; nj < 4; ++nj) {
      int col = bcol + wn * 64 + nj * 16 + lr;
#pragma unroll
      for (int r = 0; r < 4; ++r) {
        int row = brow + wm * 128 + mi * 16 + l4 + r;
        size_t idx = (size_t)row * N + col;
        float v0 = acc[mi][nj][r];
        if (EPI == 0) {
          ((u16*)Cout)[idx] = f2bu(v0);
        } else {
          float tt = v0 + bias[col];
          ((u16*)Cout)[idx] = f2bu(0.5f * tt * (1.0f + erff(tt * 0.70710678118654752f)));
        }
      }
    }
  }
}

// ---------------- bf16 GEMM, m97 structure + XCD swizzle (N=1024 GEMMs) ----------
// EPI 1: C=AB+bias+res -> f32
__global__ __launch_bounds__(256, 2) void gemm_kernel(
    const u16* __restrict__ A, const u16* __restrict__ Bt, void* Cout,
    const float* __restrict__ bias, const float* res, int M, int N, int K)
{
  __shared__ __align__(16) u16 As[2][128 * 32];
  __shared__ __align__(16) u16 Bs[2][128 * 32];
  const int tid = threadIdx.x;
  const int w = tid >> 6, l = tid & 63;
  const int gx = gridDim.x;
  const int nwg = gx * gridDim.y;
  const int orig = blockIdx.y * gx + blockIdx.x;
  const int qq = nwg >> 3, rr = nwg & 7, xcd = orig & 7, lin = orig >> 3;
  const int wg = (xcd < rr ? xcd * (qq + 1) : rr * (qq + 1) + (xcd - rr) * qq) + lin;
  const int brow = (wg / gx) << 7, bcol = (wg % gx) << 7;
  const int wr = (w >> 1) << 6, wc = (w & 1) << 6;
  const int lr = l & 15, lk = (l >> 4) << 3;
  f32x4 acc[4][4] = {};
  const int nk = K >> 5;

#define STAGE_G(buf, kt)                                                        \
  {                                                                             \
    _Pragma("unroll")                                                           \
    for (int j = 0; j < 2; ++j) {                                               \
      int c = j * 256 + tid;                                                    \
      int rrow = c >> 2, k8 = (c & 3) << 3;                                     \
      int ub = (j * 256 + w * 64) * 8;                                          \
      gload16(&As[buf][ub], A + (size_t)(brow + rrow) * K + (kt) * 32 + k8);    \
      gload16(&Bs[buf][ub], Bt + (size_t)(bcol + rrow) * K + (kt) * 32 + k8);   \
    }                                                                           \
  }

  STAGE_G(0, 0);
  __syncthreads();
  for (int kt = 0; kt < nk; ++kt) {
    int buf = kt & 1;
    if (kt + 1 < nk) STAGE_G(buf ^ 1, kt + 1);
    bf16x8 a[4], bb[4];
#pragma unroll
    for (int m = 0; m < 4; ++m) a[m] = *(const bf16x8*)&As[buf][(wr + m * 16 + lr) * 32 + lk];
#pragma unroll
    for (int n = 0; n < 4; ++n) bb[n] = *(const bf16x8*)&Bs[buf][(wc + n * 16 + lr) * 32 + lk];
#pragma unroll
    for (int m = 0; m < 4; ++m)
#pragma unroll
      for (int n = 0; n < 4; ++n)
        acc[m][n] = __builtin_amdgcn_mfma_f32_16x16x32_bf16(a[m], bb[n], acc[m][n], 0, 0, 0);
    __syncthreads();
  }
#undef STAGE_G
  const int l4 = (l >> 4) << 2;
#pragma unroll
  for (int m = 0; m < 4; ++m) {
#pragma unroll
    for (int n = 0; n < 4; ++n) {
      int col = bcol + wc + n * 16 + lr;
#pragma unroll
      for (int r = 0; r < 4; ++r) {
        int row = brow + wr + m * 16 + l4 + r;
        size_t idx = (size_t)row * N + col;
        ((float*)Cout)[idx] = acc[m][n][r] + bias[col] + res[idx];
      }
    }
  }
}

// ---------------- attention: q softmax (q rows at stride QKVN) ----------------
__global__ __launch_bounds__(256) void qsoftmax_kernel(const u16* __restrict__ qkv, u16* __restrict__ qs)
{
  const int w = threadIdx.x >> 6, l = threadIdx.x & 63;
  const size_t gid = (size_t)blockIdx.x * 4 + w;
  const size_t tok = gid >> 3;
  const int h = (int)(gid & 7);
  const u16* row = qkv + tok * QKVN + h * 128;
  u16* orow = qs + tok * DIM + h * 128;
  u32 p = *(const u32*)(row + l * 2);
  float f0 = bu2f((u16)(p & 0xffff)), f1 = bu2f((u16)(p >> 16));
  float m = fmaxf(f0, f1);
#pragma unroll
  for (int off = 32; off; off >>= 1) m = fmaxf(m, __shfl_xor(m, off));
  float e0 = expf(f0 - m), e1 = expf(f1 - m);
  float s = e0 + e1;
#pragma unroll
  for (int off = 32; off; off >>= 1) s += __shfl_xor(s, off);
  float sc = 0.08838834764831845f / s;   // (1/sqrt(128)) / sum
  u32 o = (u32)f2bu(e0 * sc) | ((u32)f2bu(e1 * sc) << 16);
  *(u32*)(orow + l * 2) = o;
}

// ---------------- exp(k), v : rows at stride QKVN -> transposed [bh][e][n] bf16 ----------------
__global__ __launch_bounds__(256) void kvt_kernel(
    const u16* __restrict__ kin, const u16* __restrict__ vin,
    u16* __restrict__ ket, u16* __restrict__ vt)
{
  __shared__ u16 T[128 * 72];
  const int tid = threadIdx.x;
  const int t64 = blockIdx.x, bh = blockIdx.y;
  const int b = bh >> 3, h = bh & 7;
  for (int pass = 0; pass < 2; ++pass) {
    const u16* src = pass ? vin : kin;
    u16* dst = pass ? vt : ket;
    if (pass) __syncthreads();
#pragma unroll
    for (int j = 0; j < 4; ++j) {
      int c = j * 256 + tid;
      int i = c >> 4, e8 = (c & 15) << 3;
      bf16x8 dv = *(const bf16x8*)(src + ((size_t)(b * NSEQ + t64 * 64 + i)) * QKVN + h * 128 + e8);
#pragma unroll
      for (int jj = 0; jj < 8; ++jj) {
        float f = bu2f((u16)dv[jj]);
        if (pass == 0) f = expf(f);
        T[(e8 + jj) * 72 + i] = f2bu(f);
      }
    }
    __syncthreads();
#pragma unroll
    for (int j = 0; j < 4; ++j) {
      int c = j * 256 + tid;
      int e = c >> 3, n8 = (c & 7) << 3;
      bf16x8 o;
#pragma unroll
      for (int jj = 0; jj < 8; ++jj) o[jj] = (short)T[e * 72 + n8 + jj];
      *(bf16x8*)(dst + ((size_t)(bh * 128 + e)) * NSEQ + t64 * 64 + n8) = o;
    }
  }
}

// ---------------- per-bucket k sums ----------------
__global__ void ksum_kernel(const u16* __restrict__ ket, float* __restrict__ Ksum)
{
  const int u = blockIdx.x, bh = blockIdx.y, e = threadIdx.x;  // 128 threads
  const u16* p = ket + ((size_t)(bh * 128 + e)) * NSEQ + u * 64;
  float s = 0.f;
#pragma unroll
  for (int i = 0; i < 64; ++i) s += bu2f(p[i]);
  Ksum[(((size_t)bh * 64 + u) << 7) + e] = s;
}

// ---------------- exclusive cumsum of k sums over buckets ----------------
__global__ void kc_kernel(const float* __restrict__ Ksum, float* __restrict__ Kc)
{
  const int bh = blockIdx.x, e = threadIdx.x;
  float run = 0.f;
  for (int u = 0; u < 64; ++u) {
    size_t i = (((size_t)bh * 64 + u) << 7) + e;
    Kc[i] = run;
    run += Ksum[i];
  }
}

// ---------------- per-bucket ctx^T[e][d] = sum_i v[i,e]*ke[i,d] (MFMA) ----------------
__global__ __launch_bounds__(256, 2) void ctx_kernel(
    const u16* __restrict__ vt, const u16* __restrict__ ket, u16* __restrict__ ctxT)
{
  __shared__ __align__(16) u16 Av[128 * 64];
  __shared__ __align__(16) u16 Bk[128 * 64];
  const int tid = threadIdx.x, w = tid >> 6, l = tid & 63;
  const int u = blockIdx.x, bh = blockIdx.y;
  const int lr = l & 15, lk = (l >> 4) << 3;
#pragma unroll
  for (int j = 0; j < 4; ++j) {
    int c = j * 256 + tid;
    int row = c >> 3, i8 = (c & 7) << 3;
    size_t goff = ((size_t)(bh * 128 + row)) * NSEQ + u * 64 + i8;
    int ub = (j * 256 + w * 64) * 8;
    gload16(&Av[ub], vt + goff);
    gload16(&Bk[ub], ket + goff);
  }
  __syncthreads();
  const int wr = (w >> 1) << 6, wc = (w & 1) << 6;
  f32x4 acc[4][4] = {};
#pragma unroll
  for (int ks = 0; ks < 2; ++ks) {
    bf16x8 a[4], bb[4];
#pragma unroll
    for (int m = 0; m < 4; ++m) a[m] = *(const bf16x8*)&Av[(wr + m * 16 + lr) * 64 + ks * 32 + lk];
#pragma unroll
    for (int n = 0; n < 4; ++n) bb[n] = *(const bf16x8*)&Bk[(wc + n * 16 + lr) * 64 + ks * 32 + lk];
#pragma unroll
    for (int m = 0; m < 4; ++m)
#pragma unroll
      for (int n = 0; n < 4; ++n)
        acc[m][n] = __builtin_amdgcn_mfma_f32_16x16x32_bf16(a[m], bb[n], acc[m][n], 0, 0, 0);
  }
  u16* out = ctxT + ((size_t)(bh * 64 + u) << 14);
  const int l4 = (l >> 4) << 2;
#pragma unroll
  for (int m = 0; m < 4; ++m)
#pragma unroll
    for (int n = 0; n < 4; ++n)
#pragma unroll
      for (int r = 0; r < 4; ++r) {
        int e = wr + m * 16 + l4 + r, d = wc + n * 16 + lr;
        out[e * 128 + d] = f2bu(acc[m][n][r]);
      }
}

// ---------------- exclusive cumsum of ctx over buckets ----------------
__global__ void cumsum_kernel(const u16* __restrict__ ctxT, u16* __restrict__ ctxc)
{
  const size_t base = ((size_t)blockIdx.y << 20) + (size_t)blockIdx.x * 256 + threadIdx.x;
  const u16* src = ctxT + base;
  u16* dst = ctxc + base;
  float run = 0.f;
  for (int u = 0; u < 64; ++u) {
    u16 cvv = src[(size_t)u << 14];
    dst[(size_t)u << 14] = f2bu(run);
    run += bu2f(cvv);
  }
}

// ---------------- out[n][e] = D_inv[n] * sum_d qs[n,d]*ctxc[d][e] (MFMA) ----------------
__global__ __launch_bounds__(256, 2) void attnout_kernel(
    const u16* __restrict__ qs, const u16* __restrict__ ctxc,
    const float* __restrict__ Kc, u16* __restrict__ aout)
{
  __shared__ __align__(16) u16 Aq[64 * 128];
  __shared__ __align__(16) u16 Bc[128 * 128];
  __shared__ float KcS[128];
  __shared__ float Dinv[64];
  const int tid = threadIdx.x, w = tid >> 6, l = tid & 63;
  const int u = blockIdx.x, bh = blockIdx.y;
  const int b = bh >> 3, h = bh & 7;
  const int lr = l & 15, lk = (l >> 4) << 3;
#pragma unroll
  for (int j = 0; j < 4; ++j) {
    int c = j * 256 + tid;
    int n = c >> 4, d8 = (c & 15) << 3;
    gload16(&Aq[(j * 256 + w * 64) * 8],
            qs + ((size_t)(b * NSEQ + u * 64 + n)) * DIM + h * 128 + d8);
  }
  const u16* csrc = ctxc + ((size_t)(bh * 64 + u) << 14);
#pragma unroll
  for (int j = 0; j < 8; ++j) {
    int c = j * 256 + tid;
    gload16(&Bc[(j * 256 + w * 64) * 8], csrc + (size_t)c * 8);
  }
  if (tid < 128) KcS[tid] = Kc[(((size_t)bh * 64 + u) << 7) + tid];
  __syncthreads();
  if (tid < 64) {
    float s = 0.f;
#pragma unroll
    for (int dd = 0; dd < 128; ++dd) {
      int d = (dd + tid * 2) & 127;   // rotate to dodge LDS bank conflicts
      s += bu2f(Aq[tid * 128 + d]) * KcS[d];
    }
    Dinv[tid] = 1.f / fmaxf(s, 1e-3f);
  }
  __syncthreads();
  f32x4 acc[4][2] = {};
#pragma unroll
  for (int ks = 0; ks < 4; ++ks) {
    bf16x8 a[4], bb[2];
#pragma unroll
    for (int m = 0; m < 4; ++m) a[m] = *(const bf16x8*)&Aq[(m * 16 + lr) * 128 + ks * 32 + lk];
#pragma unroll
    for (int n = 0; n < 2; ++n) bb[n] = *(const bf16x8*)&Bc[(w * 32 + n * 16 + lr) * 128 + ks * 32 + lk];
#pragma unroll
    for (int m = 0; m < 4; ++m)
#pragma unroll
      for (int n = 0; n < 2; ++n)
        acc[m][n] = __builtin_amdgcn_mfma_f32_16x16x32_bf16(a[m], bb[n], acc[m][n], 0, 0, 0);
  }
  const int l4 = (l >> 4) << 2;
#pragma unroll
  for (int m = 0; m < 4; ++m)
#pragma unroll
    for (int n = 0; n < 2; ++n)
#pragma unroll
      for (int r = 0; r < 4; ++r) {
        int nrow = m * 16 + l4 + r;
        int e = w * 32 + n * 16 + lr;
        float v = acc[m][n][r] * Dinv[nrow];
        aout[((size_t)(b * NSEQ + u * 64 + nrow)) * DIM + h * 128 + e] = f2bu(v);
      }
}

extern "C" void kernel_launch(void* const* d_in, const int* in_sizes, int n_in,
                              void* d_out, int out_size, void* d_ws, size_t ws_size,
                              hipStream_t stream)
{
  (void)in_sizes; (void)n_in; (void)out_size; (void)ws_size;
  const float* x_in = (const float*)d_in[0];
  const float* ln1g = (const float*)d_in[1];
  const float* ln1b = (const float*)d_in[2];
  const float* Wq   = (const float*)d_in[3];
  const float* Wk   = (const float*)d_in[4];
  const float* Wv   = (const float*)d_in[5];
  const float* Wo   = (const float*)d_in[6];
  const float* bo   = (const float*)d_in[7];
  const float* ln2g = (const float*)d_in[8];
  const float* ln2b = (const float*)d_in[9];
  const float* W1   = (const float*)d_in[10];
  const float* b1   = (const float*)d_in[11];
  const float* W2   = (const float*)d_in[12];
  const float* b2   = (const float*)d_in[13];
  float* x = (float*)d_out;

  char* ws = (char*)d_ws;
  size_t off = 0;
  auto alloc = [&](size_t bytes) -> char* {
    char* p = ws + off;
    off += (bytes + 255) & ~(size_t)255;
    return p;
  };
  const size_t SW = (size_t)6 * 1024 * 1024;   // small weight elems (per 6 layers)
  const size_t BW = (size_t)6 * 4096 * 1024;   // big weight elems
  u16* Wqkvt = (u16*)alloc(SW * 3 * 2);        // fused [6][3072][1024]
  u16* Wot = (u16*)alloc(SW * 2);
  u16* W1t = (u16*)alloc(BW * 2);
  u16* W2t = (u16*)alloc(BW * 2);
  u16* hbuf = (u16*)alloc((size_t)TOK * DIM * 2);
  u16* qsb  = (u16*)alloc((size_t)TOK * DIM * 2);
  u16* ket  = (u16*)alloc((size_t)TOK * DIM * 2);
  u16* vtb  = (u16*)alloc((size_t)TOK * DIM * 2);
  u16* ab   = (u16*)alloc((size_t)TOK * DIM * 2);
  float* Ksum = (float*)alloc((size_t)NBH * 64 * 128 * 4);
  float* Kc   = (float*)alloc((size_t)NBH * 64 * 128 * 4);
  char* R = alloc((size_t)TOK * DFF * 2);      // 67MB union region
  u16* qkvb = (u16*)R;                                   // phase 1: fused qkv bf16 [8192][3072]
  u16* ctxT = (u16*)R;                                   // phase 2: ctx buffers
  u16* ctxc = (u16*)(R + ((size_t)NBH * 64 * 128 * 128) * 2);
  u16* mid  = (u16*)R;                                   // phase 3: ffn mid

  // one-time (per call) weight transpose + bf16 conversion
  wtrans_kernel<<<dim3(32, 32, 6), 256, 0, stream>>>(Wq, Wqkvt, 1024, 1024, QKVN * 1024, 0);
  wtrans_kernel<<<dim3(32, 32, 6), 256, 0, stream>>>(Wk, Wqkvt, 1024, 1024, QKVN * 1024, 1024);
  wtrans_kernel<<<dim3(32, 32, 6), 256, 0, stream>>>(Wv, Wqkvt, 1024, 1024, QKVN * 1024, 2048);
  wtrans_kernel<<<dim3(32, 32, 6), 256, 0, stream>>>(Wo, Wot, 1024, 1024, 1024 * 1024, 0);
  wtrans_kernel<<<dim3(128, 32, 6), 256, 0, stream>>>(W1, W1t, 1024, 4096, 4096 * 1024, 0);
  wtrans_kernel<<<dim3(32, 128, 6), 256, 0, stream>>>(W2, W2t, 4096, 1024, 4096 * 1024, 0);
  hipMemcpyAsync(x, x_in, (size_t)TOK * DIM * 4, hipMemcpyDeviceToDevice, stream);

  for (int d = 0; d < 6; ++d) {
    ln_kernel<<<TOK, 256, 0, stream>>>(x, ln1g + d * DIM, ln1b + d * DIM, hbuf);
    gemm8_kernel<0><<<dim3(12, 32), 512, 0, stream>>>(hbuf, Wqkvt + (size_t)d * QKVN * 1024, qkvb, nullptr, TOK, QKVN, DIM);
    qsoftmax_kernel<<<TOK * NH / 4, 256, 0, stream>>>(qkvb, qsb);
    kvt_kernel<<<dim3(64, NBH), 256, 0, stream>>>(qkvb + 1024, qkvb + 2048, ket, vtb);
    ksum_kernel<<<dim3(64, NBH), 128, 0, stream>>>(ket, Ksum);
    kc_kernel<<<NBH, 128, 0, stream>>>(Ksum, Kc);
    ctx_kernel<<<dim3(64, NBH), 256, 0, stream>>>(vtb, ket, ctxT);
    cumsum_kernel<<<dim3(64, NBH), 256, 0, stream>>>(ctxT, ctxc);
    attnout_kernel<<<dim3(64, NBH), 256, 0, stream>>>(qsb, ctxc, Kc, ab);
    gemm_kernel<<<dim3(8, 64), 256, 0, stream>>>(ab, Wot + (size_t)d * 1024 * 1024, x, bo + d * DIM, x, TOK, DIM, DIM);
    ln_kernel<<<TOK, 256, 0, stream>>>(x, ln2g + d * DIM, ln2b + d * DIM, hbuf);
    gemm8_kernel<2><<<dim3(16, 32), 512, 0, stream>>>(hbuf, W1t + (size_t)d * DFF * 1024, mid, b1 + d * DFF, TOK, DFF, DIM);
    gemm_kernel<<<dim3(8, 64), 256, 0, stream>>>(mid, W2t + (size_t)d * DFF * 1024, x, b2 + d * DIM, x, TOK, DIM, DFF);
  }
}

// Round 6
// 2984.204 us; speedup vs baseline: 1.0558x; 1.0309x over previous
//
#include <hip/hip_runtime.h>
#include <hip/hip_bf16.h>
#include <stdint.h>

#define TOK 8192      // B*N tokens
#define DIM 1024
#define NSEQ 4096
#define NH 8
#define DHD 128
#define NU 64         // buckets
#define DFF 4096
#define NBH 16        // B*H
#define QKVN 3072     // fused q|k|v width

typedef unsigned short u16;
typedef unsigned int u32;
typedef short bf16x8 __attribute__((ext_vector_type(8)));
typedef float f32x4 __attribute__((ext_vector_type(4)));

__device__ __forceinline__ float bu2f(u16 u) { return __uint_as_float(((u32)u) << 16); }
__device__ __forceinline__ u16 f2bu(float f) {
  union { __hip_bfloat16 b; u16 u; } cv; cv.b = __float2bfloat16(f); return cv.u;
}

typedef __attribute__((address_space(1))) void gvoid_t;
typedef __attribute__((address_space(3))) void lvoid_t;
__device__ __forceinline__ void gload16(void* lds, const void* g) {
#if __has_builtin(__builtin_amdgcn_global_load_lds)
  __builtin_amdgcn_global_load_lds((const gvoid_t*)g, (lvoid_t*)lds, 16, 0, 0);
#else
  const int l = threadIdx.x & 63;
  ((uint4*)lds)[l] = *(const uint4*)g;
#endif
}

// ---------------- weight transpose + fp32->bf16 : W[K][N] -> Wt[rowOff+N][K] ----------------
__global__ __launch_bounds__(256) void wtrans_kernel(const float* __restrict__ W,
    u16* __restrict__ Wt, int K, int N, int dStride, int rowOff)
{
  __shared__ float T[32][33];
  const int tid = threadIdx.x;
  const size_t soff = (size_t)blockIdx.z * K * N;
  const size_t doff = (size_t)blockIdx.z * dStride;
  const int n0 = blockIdx.x << 5, k0 = blockIdx.y << 5;
  const int r = tid >> 3, c4 = (tid & 7) << 2;
  float4 v = *(const float4*)(W + soff + (size_t)(k0 + r) * N + n0 + c4);
  T[r][c4] = v.x; T[r][c4 + 1] = v.y; T[r][c4 + 2] = v.z; T[r][c4 + 3] = v.w;
  __syncthreads();
  u32 lo = (u32)f2bu(T[c4][r]) | ((u32)f2bu(T[c4 + 1][r]) << 16);
  u32 hi = (u32)f2bu(T[c4 + 2][r]) | ((u32)f2bu(T[c4 + 3][r]) << 16);
  *(uint2*)(Wt + doff + (size_t)(rowOff + n0 + r) * K + k0 + c4) = make_uint2(lo, hi);
}

// ---------------- layernorm fp32 -> bf16 ----------------
__global__ __launch_bounds__(256) void ln_kernel(const float* __restrict__ x,
    const float* __restrict__ g, const float* __restrict__ bt, u16* __restrict__ h)
{
  const int row = blockIdx.x, tid = threadIdx.x;
  const int w = tid >> 6, l = tid & 63;
  float4 v = ((const float4*)(x + (size_t)row * DIM))[tid];
  float s = v.x + v.y + v.z + v.w;
  float s2 = v.x * v.x + v.y * v.y + v.z * v.z + v.w * v.w;
#pragma unroll
  for (int off = 32; off; off >>= 1) { s += __shfl_down(s, off); s2 += __shfl_down(s2, off); }
  __shared__ float ps[8];
  __shared__ float mv[2];
  if (l == 0) { ps[w] = s; ps[4 + w] = s2; }
  __syncthreads();
  if (tid == 0) {
    float S = ps[0] + ps[1] + ps[2] + ps[3];
    float S2 = ps[4] + ps[5] + ps[6] + ps[7];
    float mean = S * (1.f / 1024.f);
    float var = S2 * (1.f / 1024.f) - mean * mean;
    mv[0] = mean; mv[1] = rsqrtf(var + 1e-5f);
  }
  __syncthreads();
  const float mean = mv[0], inv = mv[1];
  const int c = tid * 4;
  float o0 = (v.x - mean) * inv * g[c + 0] + bt[c + 0];
  float o1 = (v.y - mean) * inv * g[c + 1] + bt[c + 1];
  float o2 = (v.z - mean) * inv * g[c + 2] + bt[c + 2];
  float o3 = (v.w - mean) * inv * g[c + 3] + bt[c + 3];
  u32 lo = (u32)f2bu(o0) | ((u32)f2bu(o1) << 16);
  u32 hi = (u32)f2bu(o2) | ((u32)f2bu(o3) << 16);
  ((uint2*)(h + (size_t)row * DIM))[tid] = make_uint2(lo, hi);
}

// ================= 256x256 8-phase GEMM v3 =================
// Changes vs v2: (1) fragment reads via inline-asm ds_read_b128 (compiler waitcnt
// pass can't see them -> no conservative vmcnt(0) from DMA aliasing); (2) ONE
// barrier per phase: loads; lgkmcnt(0); sched_barrier(0); s_barrier; 16xMFMA;
// (3) counted vmcnt gates only at ph3/ph7. 3-bit row-XOR LDS swizzle (verified R5).
template<int EPI>
__global__ __launch_bounds__(512, 2) void gemm8_kernel(
    const u16* __restrict__ A, const u16* __restrict__ Bt, void* Cout,
    const float* __restrict__ bias, int M, int N, int K)
{
  __shared__ __align__(16) u16 As[2][2][8192];   // [dbuf][half][128*64]
  __shared__ __align__(16) u16 Bs[2][2][8192];
  const int tid = threadIdx.x;
  const int w = tid >> 6, l = tid & 63;
  const int wm = w >> 2, wn = w & 3;
  const int lr = l & 15, lk = (l >> 4) << 3;
  // bijective XCD swizzle (m204)
  const int gx = gridDim.x;
  const int nwg = gx * gridDim.y;
  const int orig = blockIdx.y * gx + blockIdx.x;
  const int qq = nwg >> 3, rr = nwg & 7, xcd = orig & 7, lin = orig >> 3;
  const int wg = (xcd < rr ? xcd * (qq + 1) : rr * (qq + 1) + (xcd - rr) * qq) + lin;
  const int brow = (wg / gx) << 8, bcol = (wg % gx) << 8;
  const int nk = K >> 6, nkp = nk >> 1;
  // staging: linear LDS dest; global source col pre-swizzled (same involution)
  const int srow = w * 8 + (l >> 3);
  const int scol = (((l & 7) ^ ((l >> 3) & 7)) << 3);
  // fragment-read swizzle: col_u16 ^= (row&7)<<3 (row&7 == l&7)
  const int rsw = (l & 7) << 3;
  const int colK0 = lk ^ rsw, colK1 = (32 + lk) ^ rsw;

  f32x4 acc[8][4] = {};
  bf16x8 af[4][2];
  bf16x8 bf[2][2][2];

#define DSR(dst_, ptr_) { u32 a_ = (u32)(size_t)(lvoid_t*)(ptr_);               \
    asm volatile("ds_read_b128 %0, %1" : "=v"(dst_) : "v"(a_)); }
#define STAGE_A8(b_, kt_) { _Pragma("unroll") for (int h_ = 0; h_ < 2; ++h_)    \
    _Pragma("unroll") for (int c = 0; c < 2; ++c)                               \
    gload16(&As[b_][h_][c * 4096 + w * 512],                                    \
      A + (size_t)(brow + h_ * 128 + c * 64 + srow) * K + (kt_) * 64 + scol); }
#define STAGE_B8(b_, kt_) { _Pragma("unroll") for (int h_ = 0; h_ < 2; ++h_)    \
    _Pragma("unroll") for (int c = 0; c < 2; ++c)                               \
    gload16(&Bs[b_][h_][c * 4096 + w * 512],                                    \
      Bt + (size_t)(bcol + h_ * 128 + c * 64 + srow) * K + (kt_) * 64 + scol); }
#define LOAD_AF(b_, mh_) { _Pragma("unroll") for (int m = 0; m < 4; ++m) {      \
    const u16* p_ = &As[b_][wm][((mh_) * 64 + m * 16 + lr) * 64];               \
    DSR(af[m][0], p_ + colK0); DSR(af[m][1], p_ + colK1); } }
#define LOAD_BF(b_, nh_) { _Pragma("unroll") for (int n = 0; n < 2; ++n) {      \
    const u16* p_ = &Bs[b_][wn >> 1][((wn & 1) * 64 + (nh_) * 32 + n * 16 + lr) * 64]; \
    DSR(bf[nh_][n][0], p_ + colK0); DSR(bf[nh_][n][1], p_ + colK1); } }
#define MFMA_Q(mh_, nh_) { __builtin_amdgcn_s_setprio(1);                       \
    _Pragma("unroll") for (int kk = 0; kk < 2; ++kk)                            \
    _Pragma("unroll") for (int m = 0; m < 4; ++m)                               \
    _Pragma("unroll") for (int n = 0; n < 2; ++n)                               \
      acc[(mh_)*4+m][(nh_)*2+n] = __builtin_amdgcn_mfma_f32_16x16x32_bf16(      \
          af[m][kk], bf[nh_][n][kk], acc[(mh_)*4+m][(nh_)*2+n], 0, 0, 0);       \
    __builtin_amdgcn_s_setprio(0); }
#define BAR() __builtin_amdgcn_s_barrier()
#define WLG() { asm volatile("s_waitcnt lgkmcnt(0)" ::: "memory");              \
    __builtin_amdgcn_sched_barrier(0); }
#define WVM4() { asm volatile("s_waitcnt vmcnt(4)" ::: "memory");               \
    __builtin_amdgcn_sched_barrier(0); }
#define WVM0() { asm volatile("s_waitcnt vmcnt(0)" ::: "memory");               \
    __builtin_amdgcn_sched_barrier(0); }

  // prologue: A(0)->b0, B(0)->b0, A(1)->b1; gate A0,B0; leave A1 in flight
  STAGE_A8(0, 0);
  STAGE_B8(0, 0);
  STAGE_A8(1, 1);
  WVM4(); BAR();

  for (int i = 0; i < nkp; ++i) {
    const int t0 = 2 * i;
    // ph0 (tile t0, buf0): frags for quad(0,0); stage B(t0+1)->b1
    LOAD_AF(0, 0); LOAD_BF(0, 0);
    STAGE_B8(1, t0 + 1);
    WLG(); BAR();
    MFMA_Q(0, 0);
    // ph1: quad(0,1)
    LOAD_BF(0, 1);
    WLG(); BAR();
    MFMA_Q(0, 1);
    // ph2: quad(1,0)
    LOAD_AF(0, 1);
    WLG(); BAR();
    MFMA_Q(1, 0);
    // ph3: quad(1,1); stage A(t0+2)->b0; gate buf1 (A(t0+1),B(t0+1) landed)
    if (t0 + 2 < nk) STAGE_A8(0, t0 + 2);
    if (i + 1 < nkp) { WVM4(); } else { WVM0(); }
    BAR();
    MFMA_Q(1, 1);
    // ph4 (tile t0+1, buf1): quad(0,0); stage B(t0+2)->b0
    LOAD_AF(1, 0); LOAD_BF(1, 0);
    if (t0 + 2 < nk) STAGE_B8(0, t0 + 2);
    WLG(); BAR();
    MFMA_Q(0, 0);
    // ph5: quad(0,1)
    LOAD_BF(1, 1);
    WLG(); BAR();
    MFMA_Q(0, 1);
    // ph6: quad(1,0)
    LOAD_AF(1, 1);
    WLG(); BAR();
    MFMA_Q(1, 0);
    // ph7: quad(1,1); stage A(t0+3)->b1; gate buf0 (A(t0+2),B(t0+2) landed)
    if (t0 + 3 < nk) STAGE_A8(1, t0 + 3);
    WVM4();
    BAR();
    MFMA_Q(1, 1);
  }
#undef DSR
#undef STAGE_A8
#undef STAGE_B8
#undef LOAD_AF
#undef LOAD_BF
#undef MFMA_Q
#undef BAR
#undef WLG
#undef WVM4
#undef WVM0

  const int l4 = (l >> 4) << 2;
#pragma unroll
  for (int mi = 0; mi < 8; ++mi) {
#pragma unroll
    for (int nj = 0; nj < 4; ++nj) {
      int col = bcol + wn * 64 + nj * 16 + lr;
#pragma unroll
      for (int r = 0; r < 4; ++r) {
        int row = brow + wm * 128 + mi * 16 + l4 + r;
        size_t idx = (size_t)row * N + col;
        float v0 = acc[mi][nj][r];
        if (EPI == 0) {
          ((u16*)Cout)[idx] = f2bu(v0);
        } else {
          float tt = v0 + bias[col];
          ((u16*)Cout)[idx] = f2bu(0.5f * tt * (1.0f + erff(tt * 0.70710678118654752f)));
        }
      }
    }
  }
}

// ---------------- bf16 GEMM, m97 structure + XCD swizzle ----------
// EPI 0: C -> bf16 ; EPI 1: C=AB+bias+res -> f32 ; EPI 2: gelu(AB+bias) -> bf16
template<int EPI>
__global__ __launch_bounds__(256, 2) void gemm_kernel(
    const u16* __restrict__ A, const u16* __restrict__ Bt, void* Cout,
    const float* __restrict__ bias, const float* res, int M, int N, int K)
{
  __shared__ __align__(16) u16 As[2][128 * 32];
  __shared__ __align__(16) u16 Bs[2][128 * 32];
  const int tid = threadIdx.x;
  const int w = tid >> 6, l = tid & 63;
  const int gx = gridDim.x;
  const int nwg = gx * gridDim.y;
  const int orig = blockIdx.y * gx + blockIdx.x;
  const int qq = nwg >> 3, rr = nwg & 7, xcd = orig & 7, lin = orig >> 3;
  const int wg = (xcd < rr ? xcd * (qq + 1) : rr * (qq + 1) + (xcd - rr) * qq) + lin;
  const int brow = (wg / gx) << 7, bcol = (wg % gx) << 7;
  const int wr = (w >> 1) << 6, wc = (w & 1) << 6;
  const int lr = l & 15, lk = (l >> 4) << 3;
  f32x4 acc[4][4] = {};
  const int nk = K >> 5;

#define STAGE_G(buf, kt)                                                        \
  {                                                                             \
    _Pragma("unroll")                                                           \
    for (int j = 0; j < 2; ++j) {                                               \
      int c = j * 256 + tid;                                                    \
      int rrow = c >> 2, k8 = (c & 3) << 3;                                     \
      int ub = (j * 256 + w * 64) * 8;                                          \
      gload16(&As[buf][ub], A + (size_t)(brow + rrow) * K + (kt) * 32 + k8);    \
      gload16(&Bs[buf][ub], Bt + (size_t)(bcol + rrow) * K + (kt) * 32 + k8);   \
    }                                                                           \
  }

  STAGE_G(0, 0);
  __syncthreads();
  for (int kt = 0; kt < nk; ++kt) {
    int buf = kt & 1;
    if (kt + 1 < nk) STAGE_G(buf ^ 1, kt + 1);
    bf16x8 a[4], bb[4];
#pragma unroll
    for (int m = 0; m < 4; ++m) a[m] = *(const bf16x8*)&As[buf][(wr + m * 16 + lr) * 32 + lk];
#pragma unroll
    for (int n = 0; n < 4; ++n) bb[n] = *(const bf16x8*)&Bs[buf][(wc + n * 16 + lr) * 32 + lk];
#pragma unroll
    for (int m = 0; m < 4; ++m)
#pragma unroll
      for (int n = 0; n < 4; ++n)
        acc[m][n] = __builtin_amdgcn_mfma_f32_16x16x32_bf16(a[m], bb[n], acc[m][n], 0, 0, 0);
    __syncthreads();
  }
#undef STAGE_G
  const int l4 = (l >> 4) << 2;
#pragma unroll
  for (int m = 0; m < 4; ++m) {
#pragma unroll
    for (int n = 0; n < 4; ++n) {
      int col = bcol + wc + n * 16 + lr;
#pragma unroll
      for (int r = 0; r < 4; ++r) {
        int row = brow + wr + m * 16 + l4 + r;
        size_t idx = (size_t)row * N + col;
        float v0 = acc[m][n][r];
        if (EPI == 0) {
          ((u16*)Cout)[idx] = f2bu(v0);
        } else if (EPI == 1) {
          ((float*)Cout)[idx] = v0 + bias[col] + res[idx];
        } else {
          float t = v0 + bias[col];
          ((u16*)Cout)[idx] = f2bu(0.5f * t * (1.0f + erff(t * 0.70710678118654752f)));
        }
      }
    }
  }
}

// ---------------- attention: q softmax (q rows at stride QKVN) ----------------
__global__ __launch_bounds__(256) void qsoftmax_kernel(const u16* __restrict__ qkv, u16* __restrict__ qs)
{
  const int w = threadIdx.x >> 6, l = threadIdx.x & 63;
  const size_t gid = (size_t)blockIdx.x * 4 + w;
  const size_t tok = gid >> 3;
  const int h = (int)(gid & 7);
  const u16* row = qkv + tok * QKVN + h * 128;
  u16* orow = qs + tok * DIM + h * 128;
  u32 p = *(const u32*)(row + l * 2);
  float f0 = bu2f((u16)(p & 0xffff)), f1 = bu2f((u16)(p >> 16));
  float m = fmaxf(f0, f1);
#pragma unroll
  for (int off = 32; off; off >>= 1) m = fmaxf(m, __shfl_xor(m, off));
  float e0 = expf(f0 - m), e1 = expf(f1 - m);
  float s = e0 + e1;
#pragma unroll
  for (int off = 32; off; off >>= 1) s += __shfl_xor(s, off);
  float sc = 0.08838834764831845f / s;   // (1/sqrt(128)) / sum
  u32 o = (u32)f2bu(e0 * sc) | ((u32)f2bu(e1 * sc) << 16);
  *(u32*)(orow + l * 2) = o;
}

// ------- exp(k), v : rows at stride QKVN -> transposed [bh][e][n] bf16 ; fused ksum -------
__global__ __launch_bounds__(256) void kvt_kernel(
    const u16* __restrict__ kin, const u16* __restrict__ vin,
    u16* __restrict__ ket, u16* __restrict__ vt, float* __restrict__ Ksum)
{
  __shared__ u16 T[128 * 72];
  const int tid = threadIdx.x;
  const int t64 = blockIdx.x, bh = blockIdx.y;
  const int b = bh >> 3, h = bh & 7;
  for (int pass = 0; pass < 2; ++pass) {
    const u16* src = pass ? vin : kin;
    u16* dst = pass ? vt : ket;
    if (pass) __syncthreads();
#pragma unroll
    for (int j = 0; j < 4; ++j) {
      int c = j * 256 + tid;
      int i = c >> 4, e8 = (c & 15) << 3;
      bf16x8 dv = *(const bf16x8*)(src + ((size_t)(b * NSEQ + t64 * 64 + i)) * QKVN + h * 128 + e8);
#pragma unroll
      for (int jj = 0; jj < 8; ++jj) {
        float f = bu2f((u16)dv[jj]);
        if (pass == 0) f = expf(f);
        T[(e8 + jj) * 72 + i] = f2bu(f);
      }
    }
    __syncthreads();
    if (pass == 0 && tid < 128) {   // fused per-bucket k-sum (bucket == t64)
      float s = 0.f;
#pragma unroll
      for (int i2 = 0; i2 < 64; ++i2) s += bu2f(T[tid * 72 + i2]);
      Ksum[(((size_t)bh * 64 + t64) << 7) + tid] = s;
    }
#pragma unroll
    for (int j = 0; j < 4; ++j) {
      int c = j * 256 + tid;
      int e = c >> 3, n8 = (c & 7) << 3;
      bf16x8 o;
#pragma unroll
      for (int jj = 0; jj < 8; ++jj) o[jj] = (short)T[e * 72 + n8 + jj];
      *(bf16x8*)(dst + ((size_t)(bh * 128 + e)) * NSEQ + t64 * 64 + n8) = o;
    }
  }
}

// ---------------- exclusive cumsum of k sums over buckets ----------------
__global__ void kc_kernel(const float* __restrict__ Ksum, float* __restrict__ Kc)
{
  const int bh = blockIdx.x, e = threadIdx.x;
  float run = 0.f;
  for (int u = 0; u < 64; ++u) {
    size_t i = (((size_t)bh * 64 + u) << 7) + e;
    Kc[i] = run;
    run += Ksum[i];
  }
}

// ---------------- per-bucket ctx^T[e][d] = sum_i v[i,e]*ke[i,d] (MFMA) ----------------
__global__ __launch_bounds__(256, 2) void ctx_kernel(
    const u16* __restrict__ vt, const u16* __restrict__ ket, u16* __restrict__ ctxT)
{
  __shared__ __align__(16) u16 Av[128 * 64];
  __shared__ __align__(16) u16 Bk[128 * 64];
  const int tid = threadIdx.x, w = tid >> 6, l = tid & 63;
  const int u = blockIdx.x, bh = blockIdx.y;
  const int lr = l & 15, lk = (l >> 4) << 3;
#pragma unroll
  for (int j = 0; j < 4; ++j) {
    int c = j * 256 + tid;
    int row = c >> 3, i8 = (c & 7) << 3;
    size_t goff = ((size_t)(bh * 128 + row)) * NSEQ + u * 64 + i8;
    int ub = (j * 256 + w * 64) * 8;
    gload16(&Av[ub], vt + goff);
    gload16(&Bk[ub], ket + goff);
  }
  __syncthreads();
  const int wr = (w >> 1) << 6, wc = (w & 1) << 6;
  f32x4 acc[4][4] = {};
#pragma unroll
  for (int ks = 0; ks < 2; ++ks) {
    bf16x8 a[4], bb[4];
#pragma unroll
    for (int m = 0; m < 4; ++m) a[m] = *(const bf16x8*)&Av[(wr + m * 16 + lr) * 64 + ks * 32 + lk];
#pragma unroll
    for (int n = 0; n < 4; ++n) bb[n] = *(const bf16x8*)&Bk[(wc + n * 16 + lr) * 64 + ks * 32 + lk];
#pragma unroll
    for (int m = 0; m < 4; ++m)
#pragma unroll
      for (int n = 0; n < 4; ++n)
        acc[m][n] = __builtin_amdgcn_mfma_f32_16x16x32_bf16(a[m], bb[n], acc[m][n], 0, 0, 0);
  }
  u16* out = ctxT + ((size_t)(bh * 64 + u) << 14);
  const int l4 = (l >> 4) << 2;
#pragma unroll
  for (int m = 0; m < 4; ++m)
#pragma unroll
    for (int n = 0; n < 4; ++n)
#pragma unroll
      for (int r = 0; r < 4; ++r) {
        int e = wr + m * 16 + l4 + r, d = wc + n * 16 + lr;
        out[e * 128 + d] = f2bu(acc[m][n][r]);
      }
}

// ---------------- exclusive cumsum of ctx over buckets ----------------
__global__ void cumsum_kernel(const u16* __restrict__ ctxT, u16* __restrict__ ctxc)
{
  const size_t base = ((size_t)blockIdx.y << 20) + (size_t)blockIdx.x * 256 + threadIdx.x;
  const u16* src = ctxT + base;
  u16* dst = ctxc + base;
  float run = 0.f;
  for (int u = 0; u < 64; ++u) {
    u16 cvv = src[(size_t)u << 14];
    dst[(size_t)u << 14] = f2bu(run);
    run += bu2f(cvv);
  }
}

// ---------------- out[n][e] = D_inv[n] * sum_d qs[n,d]*ctxc[d][e] (MFMA) ----------------
__global__ __launch_bounds__(256, 2) void attnout_kernel(
    const u16* __restrict__ qs, const u16* __restrict__ ctxc,
    const float* __restrict__ Kc, u16* __restrict__ aout)
{
  __shared__ __align__(16) u16 Aq[64 * 128];
  __shared__ __align__(16) u16 Bc[128 * 128];
  __shared__ float KcS[128];
  __shared__ float Dinv[64];
  const int tid = threadIdx.x, w = tid >> 6, l = tid & 63;
  const int u = blockIdx.x, bh = blockIdx.y;
  const int b = bh >> 3, h = bh & 7;
  const int lr = l & 15, lk = (l >> 4) << 3;
#pragma unroll
  for (int j = 0; j < 4; ++j) {
    int c = j * 256 + tid;
    int n = c >> 4, d8 = (c & 15) << 3;
    gload16(&Aq[(j * 256 + w * 64) * 8],
            qs + ((size_t)(b * NSEQ + u * 64 + n)) * DIM + h * 128 + d8);
  }
  const u16* csrc = ctxc + ((size_t)(bh * 64 + u) << 14);
#pragma unroll
  for (int j = 0; j < 8; ++j) {
    int c = j * 256 + tid;
    gload16(&Bc[(j * 256 + w * 64) * 8], csrc + (size_t)c * 8);
  }
  if (tid < 128) KcS[tid] = Kc[(((size_t)bh * 64 + u) << 7) + tid];
  __syncthreads();
  if (tid < 64) {
    float s = 0.f;
#pragma unroll
    for (int dd = 0; dd < 128; ++dd) {
      int d = (dd + tid * 2) & 127;   // rotate to dodge LDS bank conflicts
      s += bu2f(Aq[tid * 128 + d]) * KcS[d];
    }
    Dinv[tid] = 1.f / fmaxf(s, 1e-3f);
  }
  __syncthreads();
  f32x4 acc[4][2] = {};
#pragma unroll
  for (int ks = 0; ks < 4; ++ks) {
    bf16x8 a[4], bb[2];
#pragma unroll
    for (int m = 0; m < 4; ++m) a[m] = *(const bf16x8*)&Aq[(m * 16 + lr) * 128 + ks * 32 + lk];
#pragma unroll
    for (int n = 0; n < 2; ++n) bb[n] = *(const bf16x8*)&Bc[(w * 32 + n * 16 + lr) * 128 + ks * 32 + lk];
#pragma unroll
    for (int m = 0; m < 4; ++m)
#pragma unroll
      for (int n = 0; n < 2; ++n)
        acc[m][n] = __builtin_amdgcn_mfma_f32_16x16x32_bf16(a[m], bb[n], acc[m][n], 0, 0, 0);
  }
  const int l4 = (l >> 4) << 2;
#pragma unroll
  for (int m = 0; m < 4; ++m)
#pragma unroll
    for (int n = 0; n < 2; ++n)
#pragma unroll
      for (int r = 0; r < 4; ++r) {
        int nrow = m * 16 + l4 + r;
        int e = w * 32 + n * 16 + lr;
        float v = acc[m][n][r] * Dinv[nrow];
        aout[((size_t)(b * NSEQ + u * 64 + nrow)) * DIM + h * 128 + e] = f2bu(v);
      }
}

extern "C" void kernel_launch(void* const* d_in, const int* in_sizes, int n_in,
                              void* d_out, int out_size, void* d_ws, size_t ws_size,
                              hipStream_t stream)
{
  (void)in_sizes; (void)n_in; (void)out_size; (void)ws_size;
  const float* x_in = (const float*)d_in[0];
  const float* ln1g = (const float*)d_in[1];
  const float* ln1b = (const float*)d_in[2];
  const float* Wq   = (const float*)d_in[3];
  const float* Wk   = (const float*)d_in[4];
  const float* Wv   = (const float*)d_in[5];
  const float* Wo   = (const float*)d_in[6];
  const float* bo   = (const float*)d_in[7];
  const float* ln2g = (const float*)d_in[8];
  const float* ln2b = (const float*)d_in[9];
  const float* W1   = (const float*)d_in[10];
  const float* b1   = (const float*)d_in[11];
  const float* W2   = (const float*)d_in[12];
  const float* b2   = (const float*)d_in[13];
  float* x = (float*)d_out;

  char* ws = (char*)d_ws;
  size_t off = 0;
  auto alloc = [&](size_t bytes) -> char* {
    char* p = ws + off;
    off += (bytes + 255) & ~(size_t)255;
    return p;
  };
  const size_t SW = (size_t)6 * 1024 * 1024;   // small weight elems (per 6 layers)
  const size_t BW = (size_t)6 * 4096 * 1024;   // big weight elems
  u16* Wqkvt = (u16*)alloc(SW * 3 * 2);        // fused [6][3072][1024]
  u16* Wot = (u16*)alloc(SW * 2);
  u16* W1t = (u16*)alloc(BW * 2);
  u16* W2t = (u16*)alloc(BW * 2);
  u16* hbuf = (u16*)alloc((size_t)TOK * DIM * 2);
  u16* qsb  = (u16*)alloc((size_t)TOK * DIM * 2);
  u16* ket  = (u16*)alloc((size_t)TOK * DIM * 2);
  u16* vtb  = (u16*)alloc((size_t)TOK * DIM * 2);
  u16* ab   = (u16*)alloc((size_t)TOK * DIM * 2);
  float* Ksum = (float*)alloc((size_t)NBH * 64 * 128 * 4);
  float* Kc   = (float*)alloc((size_t)NBH * 64 * 128 * 4);
  char* R = alloc((size_t)TOK * DFF * 2);      // 67MB union region
  u16* qkvb = (u16*)R;                                   // phase 1: fused qkv bf16 [8192][3072]
  u16* ctxT = (u16*)R;                                   // phase 2: ctx buffers
  u16* ctxc = (u16*)(R + ((size_t)NBH * 64 * 128 * 128) * 2);
  u16* mid  = (u16*)R;                                   // phase 3: ffn mid

  // one-time (per call) weight transpose + bf16 conversion
  wtrans_kernel<<<dim3(32, 32, 6), 256, 0, stream>>>(Wq, Wqkvt, 1024, 1024, QKVN * 1024, 0);
  wtrans_kernel<<<dim3(32, 32, 6), 256, 0, stream>>>(Wk, Wqkvt, 1024, 1024, QKVN * 1024, 1024);
  wtrans_kernel<<<dim3(32, 32, 6), 256, 0, stream>>>(Wv, Wqkvt, 1024, 1024, QKVN * 1024, 2048);
  wtrans_kernel<<<dim3(32, 32, 6), 256, 0, stream>>>(Wo, Wot, 1024, 1024, 1024 * 1024, 0);
  wtrans_kernel<<<dim3(128, 32, 6), 256, 0, stream>>>(W1, W1t, 1024, 4096, 4096 * 1024, 0);
  wtrans_kernel<<<dim3(32, 128, 6), 256, 0, stream>>>(W2, W2t, 4096, 1024, 4096 * 1024, 0);
  hipMemcpyAsync(x, x_in, (size_t)TOK * DIM * 4, hipMemcpyDeviceToDevice, stream);

  for (int d = 0; d < 6; ++d) {
    ln_kernel<<<TOK, 256, 0, stream>>>(x, ln1g + d * DIM, ln1b + d * DIM, hbuf);
    gemm_kernel<0><<<dim3(24, 64), 256, 0, stream>>>(hbuf, Wqkvt + (size_t)d * QKVN * 1024, qkvb, nullptr, nullptr, TOK, QKVN, DIM);
    qsoftmax_kernel<<<TOK * NH / 4, 256, 0, stream>>>(qkvb, qsb);
    kvt_kernel<<<dim3(64, NBH), 256, 0, stream>>>(qkvb + 1024, qkvb + 2048, ket, vtb, Ksum);
    kc_kernel<<<NBH, 128, 0, stream>>>(Ksum, Kc);
    ctx_kernel<<<dim3(64, NBH), 256, 0, stream>>>(vtb, ket, ctxT);
    cumsum_kernel<<<dim3(64, NBH), 256, 0, stream>>>(ctxT, ctxc);
    attnout_kernel<<<dim3(64, NBH), 256, 0, stream>>>(qsb, ctxc, Kc, ab);
    gemm_kernel<1><<<dim3(8, 64), 256, 0, stream>>>(ab, Wot + (size_t)d * 1024 * 1024, x, bo + d * DIM, x, TOK, DIM, DIM);
    ln_kernel<<<TOK, 256, 0, stream>>>(x, ln2g + d * DIM, ln2b + d * DIM, hbuf);
    gemm8_kernel<2><<<dim3(16, 32), 512, 0, stream>>>(hbuf, W1t + (size_t)d * DFF * 1024, mid, b1 + d * DFF, TOK, DFF, DIM);
    gemm_kernel<1><<<dim3(8, 64), 256, 0, stream>>>(mid, W2t + (size_t)d * DFF * 1024, x, b2 + d * DIM, x, TOK, DIM, DFF);
  }
}